// Round 9
// baseline (150.829 us; speedup 1.0000x reference)
//
#include <hip/hip_runtime.h>

// AntiAliasInterpolation2d: depthwise 13x13 Gaussian (separable), stride 4.
// in: (32,3,512,512) fp32 ; w: (3,1,13,13) fp32 ; out: (32,3,128,128) fp32
//
// v8: v5 shape + EXPLICIT register staging for memory-level parallelism.
// Phase 1 first fills float4 v[25] with 25 back-to-back independent
// global_load_dwordx4 (no consumer in between -> all stay in flight, one
// vmcnt drain), then runs the tap reduction. v5's rolling accumulate
// consumed each load immediately -> low VGPR -> few loads in flight ->
// latency-bound ~41 us with VALU at 5%. Redundant fetch is L3-absorbed
// (R1: FETCH 55 MB), so we keep the 1536-block high-concurrency grid.

constexpr int CH = 3, H = 512, W = 512;
constexpr int OH = 128, OW = 128;
constexpr int KS = 13, KA = 6, STR = 4;
constexpr int TILE_R = 8;                      // output rows per block
constexpr int GRP = 4;                         // output rows per half
constexpr int G_ROWS = GRP * STR + (KS - STR); // 25 input rows per half
constexpr int WCH = W / 4;                     // 128 float4 chunks per row
constexpr int VBW = WCH + 4;                   // padded width (2 each side)

__global__ __launch_bounds__(256)
void aa_interp_kernel(const float* __restrict__ in,
                      const float* __restrict__ wgt,
                      float* __restrict__ out) {
    __shared__ float hsh[KS];
    __shared__ float vb[STR][TILE_R][VBW];     // polyphase + pad, 16.9 KB

    const int nc  = blockIdx.y;                // fused (n, c), 0..95
    const int bi  = blockIdx.x;                // row-band 0..15
    const int r0  = bi * TILE_R;
    const int tid = threadIdx.x;

    // Normalized 1D taps = row sums of the outer-product 2D weight.
    if (tid < KS) {
        const float* w2 = wgt + (size_t)(nc % CH) * KS * KS + (size_t)tid * KS;
        float s = 0.f;
        #pragma unroll
        for (int j = 0; j < KS; ++j) s += w2[j];
        hsh[tid] = s;
    }
    // Zero the pads: 4 phases x 8 rows x 4 pad entries = 128 entries.
    if (tid < 128) {
        const int p    = tid >> 5;
        const int orow = (tid >> 2) & 7;
        const int q    = tid & 3;
        vb[p][orow][(q < 2) ? q : 128 + q] = 0.f;   // padded idx {0,1,130,131}
    }
    __syncthreads();

    float h[KS];
    #pragma unroll
    for (int k = 0; k < KS; ++k) h[k] = hsh[k];

    // ---- Phase 1: vertical stride-4 conv ---------------------------------
    const int g = tid >> 7;                    // half 0/1 (output rows 4g..)
    const int c = tid & 127;                   // chunk column
    const float* inp = in + (size_t)nc * H * W;
    const int base = 32 * bi + 16 * g - KA;    // first input row of this half

    // (a) 25 independent unconditional loads into registers — all in flight.
    float4 v[G_ROWS];
    if (bi != 0 && bi != (OH / TILE_R - 1)) {  // interior: rows provably valid
        #pragma unroll
        for (int ir = 0; ir < G_ROWS; ++ir)
            v[ir] = ((const float4*)(inp + (size_t)(base + ir) * W))[c];
    } else {                                   // edge: clamp addr + 0/1 mask
        #pragma unroll
        for (int ir = 0; ir < G_ROWS; ++ir) {
            const int row = base + ir;
            const int rc  = min(max(row, 0), H - 1);
            v[ir] = ((const float4*)(inp + (size_t)rc * W))[c];
            if (row != rc) v[ir] = make_float4(0.f, 0.f, 0.f, 0.f);
        }
    }

    // (b) tap reduction: k = ir - 4r, compile-time resolved.
    #pragma unroll
    for (int r = 0; r < GRP; ++r) {
        float4 a = make_float4(0.f, 0.f, 0.f, 0.f);
        #pragma unroll
        for (int k = 0; k < KS; ++k) {
            const float4 t = v[STR * r + k];
            a.x += h[k] * t.x; a.y += h[k] * t.y;
            a.z += h[k] * t.z; a.w += h[k] * t.w;
        }
        const int orow = g * GRP + r;
        vb[0][orow][c + 2] = a.x;
        vb[1][orow][c + 2] = a.y;
        vb[2][orow][c + 2] = a.z;
        vb[3][orow][c + 2] = a.w;
    }
    __syncthreads();

    // ---- Phase 2: horizontal stride-4 conv from padded polyphase LDS -----
    // Output col oc, tap k: phase p=(k+2)&3, padded chunk idx oc+((k+2)>>2).
    float* op = out + (size_t)nc * OH * OW + (size_t)r0 * OW;
    #pragma unroll
    for (int i = 0; i < TILE_R * OW / 256; ++i) {   // 4 outputs per thread
        const int idx  = tid + 256 * i;
        const int orow = idx >> 7;
        const int oc   = idx & (OW - 1);
        float a = 0.f;
        #pragma unroll
        for (int k = 0; k < KS; ++k)
            a += h[k] * vb[(k + 2) & 3][orow][oc + ((k + 2) >> 2)];
        op[orow * OW + oc] = a;
    }
}

extern "C" void kernel_launch(void* const* d_in, const int* in_sizes, int n_in,
                              void* d_out, int out_size, void* d_ws, size_t ws_size,
                              hipStream_t stream) {
    const float* in  = (const float*)d_in[0];
    const float* wgt = (const float*)d_in[1];
    float* out = (float*)d_out;

    dim3 grid(OH / TILE_R, 32 * CH);           // (16, 96) = 1536 blocks
    aa_interp_kernel<<<grid, dim3(256), 0, stream>>>(in, wgt, out);
}